// Round 7
// baseline (218.049 us; speedup 1.0000x reference)
//
#include <hip/hip_runtime.h>
#include <hip/hip_bf16.h>

// MultiPropMLP on MI355X: N=1M samples, MLP 16->64->64->1, per-sample weight
// set k in [0,8) via idxs (fp32 buffers, values bf16-rounded).
// Round 7: fused sort+stage+MLP per 512-sample span, occupancy-focused.
//  - X staged into LDS in SORTED order (dest rank known from the counting
//    sort), round-5 A-frag chunk layout -> direct conflict-free ds_read_b128,
//    no sId indirection in the A chain.
//  - LDS 25.6 KB (H stride 136 B, sort scratch aliased into H3, no outBuf)
//    -> 6 blocks/CU at __launch_bounds__(256,6).
//  - b0 folded into W0B K-slot 16 (A carries 1.0 at q==2); b1 folded into
//    layer-1 MFMA C-init (b1 splat); layer 2 as MFMA vs single-column W2B.

typedef __attribute__((ext_vector_type(8))) short bfrag;   // 8 bf16 (4 VGPRs)
typedef __attribute__((ext_vector_type(4))) float ffrag;   // 4 fp32 acc

#define SPAN        512
#define NSPANS      2048
#define IMG_STRIDE  15360   // W0B 4096 | W1B 8192 | W2B 2048 | f32 b1[64],b2
#define WS_NEED     ((size_t)(8 * IMG_STRIDE))

// LDS arena (bytes)
#define XG_B    0        // 16384: [g][qh][m][8] bf16, sorted rows
#define H3_B    16384    // 8704: 4 waves x 16 rows x 136 B   (aliases sort scratch)
#define SID_B   25088    // 1024: ushort[512] sorted-rank -> original row
#define CNT_B   26112    // 64: cntS[8] | startS[8]
#define SMEM_SZ 26176

__device__ __forceinline__ unsigned short bf16r(float f) {
    unsigned int u = __float_as_uint(f);
    u += 0x7fffu + ((u >> 16) & 1u);
    return (unsigned short)(u >> 16);
}
// pack two fp32 (already exact bf16) -> u32 via byte-perm (truncation exact)
__device__ __forceinline__ unsigned int pack_trunc(float hiF, float loF) {
    return __builtin_amdgcn_perm(__float_as_uint(hiF), __float_as_uint(loF), 0x07060302u);
}
// packed RNE f32x2 -> bf16x2 (v_cvt_pk_bf16_f32)
__device__ __forceinline__ unsigned int pack_cvt(float loF, float hiF) {
    union { __hip_bfloat162 h2; unsigned int u; } c;
    c.h2 = __float22bfloat162_rn(make_float2(loF, hiF));
    return c.u;
}

// ---------- K0: per-k weight images (MFMA B-fragment order) ----------
// W0B @0    : [4 nt][64 lane][8 j] bf16, k-slot kk=q*8+j: W0 rows kk<16,
//             b0 at kk==16 (A carries 1.0), zero above.
// W1B @4096 : [4 nt][2 s][64 lane][8 j] bf16, permuted k: h=(j&3)*16+s*8+q*2+(j>>2)
// W2B @12288: [2 s][64 lane][8 j] bf16, col n==0 (l15==0) only, same permutation
// bias @14336: f32 b1[64] | b2
__global__ void k_build_images(const float* __restrict__ W0, const float* __restrict__ b0,
                               const float* __restrict__ W1, const float* __restrict__ b1,
                               const float* __restrict__ W2, const float* __restrict__ b2,
                               unsigned char* __restrict__ wsB) {
    const int k = blockIdx.x, t = threadIdx.x;
    unsigned char* img = wsB + k * IMG_STRIDE;
    unsigned short* w0b = (unsigned short*)img;
    unsigned short* w1b = (unsigned short*)(img + 4096);
    unsigned short* w2b = (unsigned short*)(img + 12288);
    float* bias = (float*)(img + 14336);
    for (int e = t; e < 2048; e += 256) {
        int j = e & 7, lane = (e >> 3) & 63, nt = e >> 9, q = lane >> 4;
        int kk = q * 8 + j, n = nt * 16 + (lane & 15);
        unsigned short v = 0;
        if (kk < 16) v = bf16r(W0[k * 1024 + kk * 64 + n]);
        else if (kk == 16) v = bf16r(b0[k * 64 + n]);
        w0b[e] = v;
    }
    for (int e = t; e < 4096; e += 256) {
        int j = e & 7, lane = (e >> 3) & 63, s = (e >> 9) & 1, nt = e >> 10, q = lane >> 4;
        int h = (j & 3) * 16 + s * 8 + q * 2 + (j >> 2);
        w1b[e] = bf16r(W1[k * 4096 + h * 64 + nt * 16 + (lane & 15)]);
    }
    for (int e = t; e < 1024; e += 256) {
        int j = e & 7, lane = (e >> 3) & 63, s = e >> 9, q = lane >> 4, l15 = lane & 15;
        int h = (j & 3) * 16 + s * 8 + q * 2 + (j >> 2);
        w2b[e] = (l15 == 0) ? bf16r(W2[k * 64 + h]) : (unsigned short)0;
    }
    if (t < 64) bias[t] = b1[k * 64 + t];
    else if (t == 64) bias[64] = b2[k];
}

// ---------- K1: fused sort + sorted-stage + MFMA MLP ----------
__global__ __launch_bounds__(256, 6) void k_fused(const int* __restrict__ idxs,
                                                  const float* __restrict__ xs,
                                                  const unsigned char* __restrict__ wsB,
                                                  float* __restrict__ out) {
    __shared__ __align__(16) unsigned char smem[SMEM_SZ];
    unsigned short* Xg = (unsigned short*)(smem + XG_B);
    unsigned short* sId = (unsigned short*)(smem + SID_B);
    int* cntS = (int*)(smem + CNT_B);
    int* startS = cntS + 8;
    int* wcnt = (int*)(smem + H3_B);        // [2][4][8], aliased into H3
    int* bsbase = wcnt + 64;                // [2][4][8]

    const int tid = threadIdx.x, lane = tid & 63, w = tid >> 6;
    const int q = lane >> 4, l15 = lane & 15;
    const int base = blockIdx.x * SPAN;

    // ---- issue X loads early (coalesced, original order): rows tid, tid+256
    const float4* xp0 = (const float4*)(xs + (size_t)(base + tid) * 16);
    const float4* xp1 = (const float4*)(xs + (size_t)(base + 256 + tid) * 16);
    float4 g0 = xp0[0], g1 = xp0[1], g2 = xp0[2], g3 = xp0[3];
    float4 g4 = xp1[0], g5 = xp1[1], g6 = xp1[2], g7 = xp1[3];

    // ---- phase S: block-local counting sort (ballot ranks, stable) ----
    int kreg[2], lrank[2];
    #pragma unroll
    for (int it = 0; it < 2; ++it) {
        int k = idxs[base + it * 256 + tid];
        kreg[it] = k;
        unsigned long long mymask = 0;
        #pragma unroll
        for (int kk = 0; kk < 8; ++kk) {
            unsigned long long m = __ballot(k == kk);
            if (k == kk) mymask = m;
            if (lane == 0) wcnt[(it * 4 + w) * 8 + kk] = (int)__popcll(m);
        }
        lrank[it] = (int)__popcll(mymask & ((1ull << lane) - 1ull));
    }
    __syncthreads();
    if (tid < 8) {
        int c = 0;
        for (int e = 0; e < 8; ++e) c += wcnt[e * 8 + tid];
        cntS[tid] = c;
    }
    __syncthreads();
    if (tid == 0) {
        int s = 0;
        for (int k = 0; k < 8; ++k) { startS[k] = s; s += cntS[k]; }
    }
    __syncthreads();
    if (tid < 64) {
        int it = tid >> 5, w2 = (tid >> 3) & 3, kk = tid & 7;
        int b = startS[kk];
        for (int e = 0; e < it * 4 + w2; ++e) b += wcnt[e * 8 + kk];
        bsbase[(it * 4 + w2) * 8 + kk] = b;
    }
    __syncthreads();

    int dest0 = bsbase[w * 8 + kreg[0]] + lrank[0];
    int dest1 = bsbase[(4 + w) * 8 + kreg[1]] + lrank[1];
    sId[dest0] = (unsigned short)tid;
    sId[dest1] = (unsigned short)(256 + tid);

    // ---- phase G: write packed rows at their sorted rank (A-frag chunks) ----
    {
        uint4 lo, hi;
        lo.x = pack_trunc(g0.y, g0.x); lo.y = pack_trunc(g0.w, g0.z);
        lo.z = pack_trunc(g1.y, g1.x); lo.w = pack_trunc(g1.w, g1.z);
        hi.x = pack_trunc(g2.y, g2.x); hi.y = pack_trunc(g2.w, g2.z);
        hi.z = pack_trunc(g3.y, g3.x); hi.w = pack_trunc(g3.w, g3.z);
        int g = dest0 >> 4, m = dest0 & 15;
        *(uint4*)(Xg + g * 256 + m * 8)       = lo;
        *(uint4*)(Xg + g * 256 + 128 + m * 8) = hi;
        lo.x = pack_trunc(g4.y, g4.x); lo.y = pack_trunc(g4.w, g4.z);
        lo.z = pack_trunc(g5.y, g5.x); lo.w = pack_trunc(g5.w, g5.z);
        hi.x = pack_trunc(g6.y, g6.x); hi.y = pack_trunc(g6.w, g6.z);
        hi.z = pack_trunc(g7.y, g7.x); hi.w = pack_trunc(g7.w, g7.z);
        g = dest1 >> 4; m = dest1 & 15;
        *(uint4*)(Xg + g * 256 + m * 8)       = lo;
        *(uint4*)(Xg + g * 256 + 128 + m * 8) = hi;
    }
    __syncthreads();

    // ---- phase M: wave w processes buckets k = w, w+4 ----
    unsigned char* H = smem + H3_B + w * 2176;   // 16 rows x 136 B
    const ffrag z = {0.f, 0.f, 0.f, 0.f};
    #pragma unroll
    for (int kk2 = 0; kk2 < 2; ++kk2) {
        const int k = w + kk2 * 4;
        const int cnt = cntS[k];
        if (cnt == 0) continue;
        const int start = startS[k];
        const unsigned char* img = wsB + k * IMG_STRIDE;

        bfrag w0f[4], w1f[4][2], w2f[2];
        #pragma unroll
        for (int nt = 0; nt < 4; ++nt)
            w0f[nt] = *(const bfrag*)(img + nt * 1024 + lane * 16);
        #pragma unroll
        for (int nt = 0; nt < 4; ++nt)
            #pragma unroll
            for (int s = 0; s < 2; ++s)
                w1f[nt][s] = *(const bfrag*)(img + 4096 + ((nt * 2 + s) * 64 + lane) * 16);
        #pragma unroll
        for (int s = 0; s < 2; ++s)
            w2f[s] = *(const bfrag*)(img + 12288 + (s * 64 + lane) * 16);
        const float* bias = (const float*)(img + 14336);
        float b1v[4];
        #pragma unroll
        for (int nt = 0; nt < 4; ++nt) b1v[nt] = bias[nt * 16 + l15];
        const float b2v = bias[64];

        const int nst = (cnt + 15) >> 4;
        for (int st = 0; st < nst; ++st) {
            // ---- A fragment: direct sorted-Xg read (conflict-free) ----
            int R = start + st * 16 + l15;
            int Rm = start + cnt - 1;
            R = R < Rm ? R : Rm;
            bfrag a = {0, 0, 0, 0, 0, 0, 0, 0};
            if (q < 2)
                a = *(const bfrag*)(Xg + (R >> 4) * 256 + q * 128 + (R & 15) * 8);
            else if (q == 2)
                a[0] = (short)0x3F80;   // bf16 1.0 (bias dim, K-slot 16)

            // ---- layer 0 (+b0): 4 x mfma 16x16x32 ----
            ffrag acc0[4];
            #pragma unroll
            for (int nt = 0; nt < 4; ++nt)
                acc0[nt] = __builtin_amdgcn_mfma_f32_16x16x32_bf16(a, w0f[nt], z, 0, 0, 0);

            // ---- H1 = relu(acc0) -> LDS (permuted slots, stride 136 B) ----
            #pragma unroll
            for (int r = 0; r < 4; ++r) {
                float v0 = acc0[0][r]; v0 = v0 > 0.f ? v0 : 0.f;
                float v1 = acc0[1][r]; v1 = v1 > 0.f ? v1 : 0.f;
                float v2 = acc0[2][r]; v2 = v2 > 0.f ? v2 : 0.f;
                float v3 = acc0[3][r]; v3 = v3 > 0.f ? v3 : 0.f;
                uint2 u;
                u.x = pack_cvt(v0, v1);
                u.y = pack_cvt(v2, v3);
                *(uint2*)(H + (q * 4 + r) * 136 + l15 * 8) = u;
            }

            // ---- layer 1: 8 x mfma, b1 folded into C-init (splat) ----
            bfrag a10 = *(const bfrag*)(H + l15 * 136 + q * 16);
            bfrag a11 = *(const bfrag*)(H + l15 * 136 + 64 + q * 16);
            ffrag acc1[4];
            #pragma unroll
            for (int nt = 0; nt < 4; ++nt) {
                ffrag c1 = {b1v[nt], b1v[nt], b1v[nt], b1v[nt]};
                acc1[nt] = __builtin_amdgcn_mfma_f32_16x16x32_bf16(a10, w1f[nt][0], c1, 0, 0, 0);
                acc1[nt] = __builtin_amdgcn_mfma_f32_16x16x32_bf16(a11, w1f[nt][1], acc1[nt], 0, 0, 0);
            }

            // ---- H2 = relu(acc1) -> same LDS slots ----
            #pragma unroll
            for (int r = 0; r < 4; ++r) {
                float v0 = acc1[0][r]; v0 = v0 > 0.f ? v0 : 0.f;
                float v1 = acc1[1][r]; v1 = v1 > 0.f ? v1 : 0.f;
                float v2 = acc1[2][r]; v2 = v2 > 0.f ? v2 : 0.f;
                float v3 = acc1[3][r]; v3 = v3 > 0.f ? v3 : 0.f;
                uint2 u;
                u.x = pack_cvt(v0, v1);
                u.y = pack_cvt(v2, v3);
                *(uint2*)(H + (q * 4 + r) * 136 + l15 * 8) = u;
            }

            // ---- layer 2: 2 x mfma vs single-column W2B ----
            bfrag a20 = *(const bfrag*)(H + l15 * 136 + q * 16);
            bfrag a21 = *(const bfrag*)(H + l15 * 136 + 64 + q * 16);
            ffrag d = __builtin_amdgcn_mfma_f32_16x16x32_bf16(a20, w2f[0], z, 0, 0, 0);
            d = __builtin_amdgcn_mfma_f32_16x16x32_bf16(a21, w2f[1], d, 0, 0, 0);

            // ---- store: col 0 lives in lanes l15==0, rows m = q*4+r ----
            if (l15 == 0) {
                #pragma unroll
                for (int r = 0; r < 4; ++r) {
                    int row = st * 16 + q * 4 + r;
                    if (row < cnt) {
                        int oid = (int)sId[start + row];
                        out[base + oid] = d[r] + b2v;
                    }
                }
            }
        }
    }
}

// ---------- fallback: per-thread fp32 ----------
__global__ void k_fallback(const int* __restrict__ idxs, const float* __restrict__ xs,
                           const float* __restrict__ W0, const float* __restrict__ b0,
                           const float* __restrict__ W1, const float* __restrict__ b1,
                           const float* __restrict__ W2, const float* __restrict__ b2,
                           float* __restrict__ out, int N) {
    int n = blockIdx.x * blockDim.x + threadIdx.x;
    if (n >= N) return;
    int k = idxs[n];
    float h0[64];
    #pragma unroll
    for (int j = 0; j < 64; ++j) h0[j] = b0[k * 64 + j];
    for (int i = 0; i < 16; ++i) {
        float xi = xs[(size_t)n * 16 + i];
        #pragma unroll
        for (int j = 0; j < 64; ++j) h0[j] = fmaf(xi, W0[k * 1024 + i * 64 + j], h0[j]);
    }
    #pragma unroll
    for (int j = 0; j < 64; ++j) h0[j] = fmaxf(h0[j], 0.f);
    float acc = b2[k];
    for (int jc = 0; jc < 4; ++jc) {
        float h1[16];
        #pragma unroll
        for (int j = 0; j < 16; ++j) h1[j] = b1[k * 64 + jc * 16 + j];
        for (int i = 0; i < 64; ++i) {
            float hv = h0[i];
            #pragma unroll
            for (int j = 0; j < 16; ++j)
                h1[j] = fmaf(hv, W1[k * 4096 + i * 64 + jc * 16 + j], h1[j]);
        }
        #pragma unroll
        for (int j = 0; j < 16; ++j) acc = fmaf(fmaxf(h1[j], 0.f), W2[k * 64 + jc * 16 + j], acc);
    }
    out[n] = acc;
}

extern "C" void kernel_launch(void* const* d_in, const int* in_sizes, int n_in,
                              void* d_out, int out_size, void* d_ws, size_t ws_size,
                              hipStream_t stream) {
    const int*   idxs = (const int*)d_in[0];
    const float* xs   = (const float*)d_in[1];
    const float* W0   = (const float*)d_in[2];
    const float* b0   = (const float*)d_in[3];
    const float* W1   = (const float*)d_in[4];
    const float* b1   = (const float*)d_in[5];
    const float* W2   = (const float*)d_in[6];
    const float* b2   = (const float*)d_in[7];
    float* out = (float*)d_out;
    const int N = in_sizes[0];  // 1,048,576

    if (N != SPAN * NSPANS || ws_size < WS_NEED) {
        k_fallback<<<(N + 255) / 256, 256, 0, stream>>>(idxs, xs, W0, b0, W1, b1, W2, b2, out, N);
        return;
    }

    unsigned char* wsB = (unsigned char*)d_ws;
    k_build_images<<<8, 256, 0, stream>>>(W0, b0, W1, b1, W2, b2, wsB);
    k_fused<<<NSPANS, 256, 0, stream>>>(idxs, xs, wsB, out);
}

// Round 8
// 174.622 us; speedup vs baseline: 1.2487x; 1.2487x over previous
//
#include <hip/hip_runtime.h>
#include <hip/hip_bf16.h>

// MultiPropMLP on MI355X: N=1M samples, MLP 16->64->64->1, per-sample weight
// set k in [0,8) via idxs (fp32 buffers, values bf16-rounded).
// Round 8: round-7 structure (sorted LDS staging, conflict-free A reads,
// folded biases, MFMA layer 2) + RESTORED LDS outBuf staging and coalesced
// final write (round-7's direct scattered 4B stores caused 30x write
// amplification: WRITE_SIZE 4->118 MB, k_fused 46->125 us).

typedef __attribute__((ext_vector_type(8))) short bfrag;   // 8 bf16 (4 VGPRs)
typedef __attribute__((ext_vector_type(4))) float ffrag;   // 4 fp32 acc

#define SPAN        512
#define NSPANS      2048
#define IMG_STRIDE  15360   // W0B 4096 | W1B 8192 | W2B 2048 | f32 b1[64],b2
#define WS_NEED     ((size_t)(8 * IMG_STRIDE))

// LDS arena (bytes)
#define XG_B    0        // 16384: [g][qh][m][8] bf16, sorted rows
#define H3_B    16384    // 8704: 4 waves x 16 rows x 136 B (aliases sort scratch)
#define SID_B   25088    // 1024: ushort[512] sorted-rank -> original row
#define CNT_B   26112    // 64: cntS[8] | startS[8]
#define OUT_B   26176    // 2048: staged outputs (original row order)
#define SMEM_SZ 28224

__device__ __forceinline__ unsigned short bf16r(float f) {
    unsigned int u = __float_as_uint(f);
    u += 0x7fffu + ((u >> 16) & 1u);
    return (unsigned short)(u >> 16);
}
// pack two fp32 (already exact bf16) -> u32 via byte-perm (truncation exact)
__device__ __forceinline__ unsigned int pack_trunc(float hiF, float loF) {
    return __builtin_amdgcn_perm(__float_as_uint(hiF), __float_as_uint(loF), 0x07060302u);
}
// packed RNE f32x2 -> bf16x2 (v_cvt_pk_bf16_f32)
__device__ __forceinline__ unsigned int pack_cvt(float loF, float hiF) {
    union { __hip_bfloat162 h2; unsigned int u; } c;
    c.h2 = __float22bfloat162_rn(make_float2(loF, hiF));
    return c.u;
}

// ---------- K0: per-k weight images (MFMA B-fragment order) ----------
// W0B @0    : [4 nt][64 lane][8 j] bf16, k-slot kk=q*8+j: W0 rows kk<16,
//             b0 at kk==16 (A carries 1.0), zero above.
// W1B @4096 : [4 nt][2 s][64 lane][8 j] bf16, permuted k: h=(j&3)*16+s*8+q*2+(j>>2)
// W2B @12288: [2 s][64 lane][8 j] bf16, col n==0 (l15==0) only, same permutation
// bias @14336: f32 b1[64] | b2
__global__ void k_build_images(const float* __restrict__ W0, const float* __restrict__ b0,
                               const float* __restrict__ W1, const float* __restrict__ b1,
                               const float* __restrict__ W2, const float* __restrict__ b2,
                               unsigned char* __restrict__ wsB) {
    const int k = blockIdx.x, t = threadIdx.x;
    unsigned char* img = wsB + k * IMG_STRIDE;
    unsigned short* w0b = (unsigned short*)img;
    unsigned short* w1b = (unsigned short*)(img + 4096);
    unsigned short* w2b = (unsigned short*)(img + 12288);
    float* bias = (float*)(img + 14336);
    for (int e = t; e < 2048; e += 256) {
        int j = e & 7, lane = (e >> 3) & 63, nt = e >> 9, q = lane >> 4;
        int kk = q * 8 + j, n = nt * 16 + (lane & 15);
        unsigned short v = 0;
        if (kk < 16) v = bf16r(W0[k * 1024 + kk * 64 + n]);
        else if (kk == 16) v = bf16r(b0[k * 64 + n]);
        w0b[e] = v;
    }
    for (int e = t; e < 4096; e += 256) {
        int j = e & 7, lane = (e >> 3) & 63, s = (e >> 9) & 1, nt = e >> 10, q = lane >> 4;
        int h = (j & 3) * 16 + s * 8 + q * 2 + (j >> 2);
        w1b[e] = bf16r(W1[k * 4096 + h * 64 + nt * 16 + (lane & 15)]);
    }
    for (int e = t; e < 1024; e += 256) {
        int j = e & 7, lane = (e >> 3) & 63, s = e >> 9, q = lane >> 4, l15 = lane & 15;
        int h = (j & 3) * 16 + s * 8 + q * 2 + (j >> 2);
        w2b[e] = (l15 == 0) ? bf16r(W2[k * 64 + h]) : (unsigned short)0;
    }
    if (t < 64) bias[t] = b1[k * 64 + t];
    else if (t == 64) bias[64] = b2[k];
}

// ---------- K1: fused sort + sorted-stage + MFMA MLP + staged write ----------
__global__ __launch_bounds__(256, 5) void k_fused(const int* __restrict__ idxs,
                                                  const float* __restrict__ xs,
                                                  const unsigned char* __restrict__ wsB,
                                                  float* __restrict__ out) {
    __shared__ __align__(16) unsigned char smem[SMEM_SZ];
    unsigned short* Xg = (unsigned short*)(smem + XG_B);
    unsigned short* sId = (unsigned short*)(smem + SID_B);
    int* cntS = (int*)(smem + CNT_B);
    int* startS = cntS + 8;
    float* outBuf = (float*)(smem + OUT_B);
    int* wcnt = (int*)(smem + H3_B);        // [2][4][8], aliased into H3
    int* bsbase = wcnt + 64;                // [2][4][8]

    const int tid = threadIdx.x, lane = tid & 63, w = tid >> 6;
    const int q = lane >> 4, l15 = lane & 15;
    const int base = blockIdx.x * SPAN;

    // ---- issue X loads early (coalesced, original order): rows tid, tid+256
    const float4* xp0 = (const float4*)(xs + (size_t)(base + tid) * 16);
    const float4* xp1 = (const float4*)(xs + (size_t)(base + 256 + tid) * 16);
    float4 g0 = xp0[0], g1 = xp0[1], g2 = xp0[2], g3 = xp0[3];
    float4 g4 = xp1[0], g5 = xp1[1], g6 = xp1[2], g7 = xp1[3];

    // ---- phase S: block-local counting sort (ballot ranks, stable) ----
    int kreg[2], lrank[2];
    #pragma unroll
    for (int it = 0; it < 2; ++it) {
        int k = idxs[base + it * 256 + tid];
        kreg[it] = k;
        unsigned long long mymask = 0;
        #pragma unroll
        for (int kk = 0; kk < 8; ++kk) {
            unsigned long long m = __ballot(k == kk);
            if (k == kk) mymask = m;
            if (lane == 0) wcnt[(it * 4 + w) * 8 + kk] = (int)__popcll(m);
        }
        lrank[it] = (int)__popcll(mymask & ((1ull << lane) - 1ull));
    }
    __syncthreads();
    if (tid < 8) {
        int c = 0;
        for (int e = 0; e < 8; ++e) c += wcnt[e * 8 + tid];
        cntS[tid] = c;
    }
    __syncthreads();
    if (tid == 0) {
        int s = 0;
        for (int k = 0; k < 8; ++k) { startS[k] = s; s += cntS[k]; }
    }
    __syncthreads();
    if (tid < 64) {
        int it = tid >> 5, w2 = (tid >> 3) & 3, kk = tid & 7;
        int b = startS[kk];
        for (int e = 0; e < it * 4 + w2; ++e) b += wcnt[e * 8 + kk];
        bsbase[(it * 4 + w2) * 8 + kk] = b;
    }
    __syncthreads();

    int dest0 = bsbase[w * 8 + kreg[0]] + lrank[0];
    int dest1 = bsbase[(4 + w) * 8 + kreg[1]] + lrank[1];
    sId[dest0] = (unsigned short)tid;
    sId[dest1] = (unsigned short)(256 + tid);

    // ---- phase G: write packed rows at their sorted rank (A-frag chunks) ----
    {
        uint4 lo, hi;
        lo.x = pack_trunc(g0.y, g0.x); lo.y = pack_trunc(g0.w, g0.z);
        lo.z = pack_trunc(g1.y, g1.x); lo.w = pack_trunc(g1.w, g1.z);
        hi.x = pack_trunc(g2.y, g2.x); hi.y = pack_trunc(g2.w, g2.z);
        hi.z = pack_trunc(g3.y, g3.x); hi.w = pack_trunc(g3.w, g3.z);
        int g = dest0 >> 4, m = dest0 & 15;
        *(uint4*)(Xg + g * 256 + m * 8)       = lo;
        *(uint4*)(Xg + g * 256 + 128 + m * 8) = hi;
        lo.x = pack_trunc(g4.y, g4.x); lo.y = pack_trunc(g4.w, g4.z);
        lo.z = pack_trunc(g5.y, g5.x); lo.w = pack_trunc(g5.w, g5.z);
        hi.x = pack_trunc(g6.y, g6.x); hi.y = pack_trunc(g6.w, g6.z);
        hi.z = pack_trunc(g7.y, g7.x); hi.w = pack_trunc(g7.w, g7.z);
        g = dest1 >> 4; m = dest1 & 15;
        *(uint4*)(Xg + g * 256 + m * 8)       = lo;
        *(uint4*)(Xg + g * 256 + 128 + m * 8) = hi;
    }
    __syncthreads();

    // ---- phase M: wave w processes buckets k = w, w+4 ----
    unsigned char* H = smem + H3_B + w * 2176;   // 16 rows x 136 B
    const ffrag z = {0.f, 0.f, 0.f, 0.f};
    #pragma unroll
    for (int kk2 = 0; kk2 < 2; ++kk2) {
        const int k = w + kk2 * 4;
        const int cnt = cntS[k];
        if (cnt == 0) continue;
        const int start = startS[k];
        const unsigned char* img = wsB + k * IMG_STRIDE;

        bfrag w0f[4], w1f[4][2], w2f[2];
        #pragma unroll
        for (int nt = 0; nt < 4; ++nt)
            w0f[nt] = *(const bfrag*)(img + nt * 1024 + lane * 16);
        #pragma unroll
        for (int nt = 0; nt < 4; ++nt)
            #pragma unroll
            for (int s = 0; s < 2; ++s)
                w1f[nt][s] = *(const bfrag*)(img + 4096 + ((nt * 2 + s) * 64 + lane) * 16);
        #pragma unroll
        for (int s = 0; s < 2; ++s)
            w2f[s] = *(const bfrag*)(img + 12288 + (s * 64 + lane) * 16);
        const float* bias = (const float*)(img + 14336);
        float b1v[4];
        #pragma unroll
        for (int nt = 0; nt < 4; ++nt) b1v[nt] = bias[nt * 16 + l15];
        const float b2v = bias[64];

        const int nst = (cnt + 15) >> 4;
        for (int st = 0; st < nst; ++st) {
            // ---- A fragment: direct sorted-Xg read (conflict-free) ----
            int R = start + st * 16 + l15;
            int Rm = start + cnt - 1;
            R = R < Rm ? R : Rm;
            bfrag a = {0, 0, 0, 0, 0, 0, 0, 0};
            if (q < 2)
                a = *(const bfrag*)(Xg + (R >> 4) * 256 + q * 128 + (R & 15) * 8);
            else if (q == 2)
                a[0] = (short)0x3F80;   // bf16 1.0 (bias dim, K-slot 16)

            // ---- layer 0 (+b0): 4 x mfma 16x16x32 ----
            ffrag acc0[4];
            #pragma unroll
            for (int nt = 0; nt < 4; ++nt)
                acc0[nt] = __builtin_amdgcn_mfma_f32_16x16x32_bf16(a, w0f[nt], z, 0, 0, 0);

            // ---- H1 = relu(acc0) -> LDS (permuted slots, stride 136 B) ----
            #pragma unroll
            for (int r = 0; r < 4; ++r) {
                float v0 = acc0[0][r]; v0 = v0 > 0.f ? v0 : 0.f;
                float v1 = acc0[1][r]; v1 = v1 > 0.f ? v1 : 0.f;
                float v2 = acc0[2][r]; v2 = v2 > 0.f ? v2 : 0.f;
                float v3 = acc0[3][r]; v3 = v3 > 0.f ? v3 : 0.f;
                uint2 u;
                u.x = pack_cvt(v0, v1);
                u.y = pack_cvt(v2, v3);
                *(uint2*)(H + (q * 4 + r) * 136 + l15 * 8) = u;
            }

            // ---- layer 1: 8 x mfma, b1 folded into C-init (splat) ----
            bfrag a10 = *(const bfrag*)(H + l15 * 136 + q * 16);
            bfrag a11 = *(const bfrag*)(H + l15 * 136 + 64 + q * 16);
            ffrag acc1[4];
            #pragma unroll
            for (int nt = 0; nt < 4; ++nt) {
                ffrag c1 = {b1v[nt], b1v[nt], b1v[nt], b1v[nt]};
                acc1[nt] = __builtin_amdgcn_mfma_f32_16x16x32_bf16(a10, w1f[nt][0], c1, 0, 0, 0);
                acc1[nt] = __builtin_amdgcn_mfma_f32_16x16x32_bf16(a11, w1f[nt][1], acc1[nt], 0, 0, 0);
            }

            // ---- H2 = relu(acc1) -> same LDS slots ----
            #pragma unroll
            for (int r = 0; r < 4; ++r) {
                float v0 = acc1[0][r]; v0 = v0 > 0.f ? v0 : 0.f;
                float v1 = acc1[1][r]; v1 = v1 > 0.f ? v1 : 0.f;
                float v2 = acc1[2][r]; v2 = v2 > 0.f ? v2 : 0.f;
                float v3 = acc1[3][r]; v3 = v3 > 0.f ? v3 : 0.f;
                uint2 u;
                u.x = pack_cvt(v0, v1);
                u.y = pack_cvt(v2, v3);
                *(uint2*)(H + (q * 4 + r) * 136 + l15 * 8) = u;
            }

            // ---- layer 2: 2 x mfma vs single-column W2B ----
            bfrag a20 = *(const bfrag*)(H + l15 * 136 + q * 16);
            bfrag a21 = *(const bfrag*)(H + l15 * 136 + 64 + q * 16);
            ffrag d = __builtin_amdgcn_mfma_f32_16x16x32_bf16(a20, w2f[0], z, 0, 0, 0);
            d = __builtin_amdgcn_mfma_f32_16x16x32_bf16(a21, w2f[1], d, 0, 0, 0);

            // ---- stage into LDS outBuf (original row order) ----
            if (l15 == 0) {
                #pragma unroll
                for (int r = 0; r < 4; ++r) {
                    int row = st * 16 + q * 4 + r;
                    if (row < cnt) {
                        int oid = (int)sId[start + row];
                        outBuf[oid] = d[r] + b2v;
                    }
                }
            }
        }
    }
    __syncthreads();

    // ---- phase O: coalesced out write (512 floats, 2 KB) ----
    ((float2*)(out + base))[tid] = ((const float2*)outBuf)[tid];
}

// ---------- fallback: per-thread fp32 ----------
__global__ void k_fallback(const int* __restrict__ idxs, const float* __restrict__ xs,
                           const float* __restrict__ W0, const float* __restrict__ b0,
                           const float* __restrict__ W1, const float* __restrict__ b1,
                           const float* __restrict__ W2, const float* __restrict__ b2,
                           float* __restrict__ out, int N) {
    int n = blockIdx.x * blockDim.x + threadIdx.x;
    if (n >= N) return;
    int k = idxs[n];
    float h0[64];
    #pragma unroll
    for (int j = 0; j < 64; ++j) h0[j] = b0[k * 64 + j];
    for (int i = 0; i < 16; ++i) {
        float xi = xs[(size_t)n * 16 + i];
        #pragma unroll
        for (int j = 0; j < 64; ++j) h0[j] = fmaf(xi, W0[k * 1024 + i * 64 + j], h0[j]);
    }
    #pragma unroll
    for (int j = 0; j < 64; ++j) h0[j] = fmaxf(h0[j], 0.f);
    float acc = b2[k];
    for (int jc = 0; jc < 4; ++jc) {
        float h1[16];
        #pragma unroll
        for (int j = 0; j < 16; ++j) h1[j] = b1[k * 64 + jc * 16 + j];
        for (int i = 0; i < 64; ++i) {
            float hv = h0[i];
            #pragma unroll
            for (int j = 0; j < 16; ++j)
                h1[j] = fmaf(hv, W1[k * 4096 + i * 64 + jc * 16 + j], h1[j]);
        }
        #pragma unroll
        for (int j = 0; j < 16; ++j) acc = fmaf(fmaxf(h1[j], 0.f), W2[k * 64 + jc * 16 + j], acc);
    }
    out[n] = acc;
}

extern "C" void kernel_launch(void* const* d_in, const int* in_sizes, int n_in,
                              void* d_out, int out_size, void* d_ws, size_t ws_size,
                              hipStream_t stream) {
    const int*   idxs = (const int*)d_in[0];
    const float* xs   = (const float*)d_in[1];
    const float* W0   = (const float*)d_in[2];
    const float* b0   = (const float*)d_in[3];
    const float* W1   = (const float*)d_in[4];
    const float* b1   = (const float*)d_in[5];
    const float* W2   = (const float*)d_in[6];
    const float* b2   = (const float*)d_in[7];
    float* out = (float*)d_out;
    const int N = in_sizes[0];  // 1,048,576

    if (N != SPAN * NSPANS || ws_size < WS_NEED) {
        k_fallback<<<(N + 255) / 256, 256, 0, stream>>>(idxs, xs, W0, b0, W1, b1, W2, b2, out, N);
        return;
    }

    unsigned char* wsB = (unsigned char*)d_ws;
    k_build_images<<<8, 256, 0, stream>>>(W0, b0, W1, b1, W2, b2, wsB);
    k_fused<<<NSPANS, 256, 0, stream>>>(idxs, xs, wsB, out);
}